// Round 6
// baseline (246.879 us; speedup 1.0000x reference)
//
#include <hip/hip_runtime.h>
#include <hip/hip_fp16.h>

#define DD 192
#define HH 192
#define WW 192
#define NVOX (DD * HH * WW)

// 32x16x8 tiles, halo 8: fp16 window x48 [-8,+40), y33 [-8,+25), z25 [-8,+17)
// staged into a 32-deep circular z-slab buffer (slab = z & 31). Consecutive
// tiles in a z-column roll: only 8 new slabs are DMA'd per tile.
#define TX 32
#define TY 16
#define TZ 8
#define RSX 48
#define RSY 33
#define RSZ 25                     // live window depth (slabs)
#define DEPTH 32                   // circular buffer depth (pow2)
#define ROWD 24                    // dwords per x-row (48 halves)
#define SLABD (RSY * ROWD)         // 792 dwords per z-slab
#define CHROW 6                    // 16B chunks per x-row
#define CHSLAB (RSY * CHROW)       // 198 chunks per slab
#define NT 1024
#define GRID 256                   // persistent: 1 block per CU

#define AS1 __attribute__((address_space(1)))
#define AS3 __attribute__((address_space(3)))

// counted vmcnt: loads stay in flight across raw barriers (T3/T4 pattern)
#define WAITCNT(n) asm volatile("s_waitcnt vmcnt(" #n ")" ::: "memory")

typedef float f32x4 __attribute__((ext_vector_type(4)));
typedef int   i32x4 __attribute__((ext_vector_type(4)));

// ---- mov fp32 -> fp16 (contiguous, BW-bound, runs once per launch) ----
__global__ __launch_bounds__(256) void conv_fp16(
    const float4* __restrict__ in, int4* __restrict__ out)
{
    const int i = blockIdx.x * 256 + threadIdx.x;
    const float4 a = in[2 * i];
    const float4 b = in[2 * i + 1];
    __half2 h0 = __floats2half2_rn(a.x, a.y);
    __half2 h1 = __floats2half2_rn(a.z, a.w);
    __half2 h2 = __floats2half2_rn(b.x, b.y);
    __half2 h3 = __floats2half2_rn(b.z, b.w);
    int4 o;
    o.x = *(int*)&h0; o.y = *(int*)&h1; o.z = *(int*)&h2; o.w = *(int*)&h3;
    out[i] = o;
}

struct Streams { f32x4 dz, dy, dx, f; i32x4 m; };

// tile decode: n -> (tx,ty,tz) global tile coords + tzi (z index in column).
// Column-major with tz fastest: consecutive tiles share 17/25 slabs -> roll.
__device__ __forceinline__ void tile_coords_col(
    int n, int OX, int OY, int OZ, int& tx, int& ty, int& tz, int& tzi)
{
    const int c = n / 12;
    tzi = n - c * 12;
    const int ox = c / 6;
    tx = OX + ox;
    ty = OY + (c - ox * 6);
    tz = OZ + tzi;
}

// Stage nslab z-slabs [z_first, z_first+nslab) into the circular buffer.
// Per-slab dispatch (128 threads per slab) keeps each wave's LDS destinations
// linear within ONE slab — required because global_load_lds writes at
// wave-uniform base + lane*16, and the circular wrap breaks cross-slab
// linearity. OOB chunks redirect their global source to zbuf (zeros).
// Per-wave vmem count: <=2 (roll, nslab=8) / <=8 (restage, nslab=25).
__device__ __forceinline__ void stage_slabs(
    const ushort* __restrict__ movh, const ushort* __restrict__ zbuf,
    uint* sbufd, int x_lo, int y_lo, int z_first, int nslab, int tid)
{
    ushort* sbuf = (ushort*)sbufd;
    const int sg = tid >> 7;        // slab group 0..7 (wave-uniform)
    const int lq = tid & 127;       // chunk lane within slab
    for (int it = 0; it < (nslab + 7) / 8; ++it) {
        const int j = it * 8 + sg;  // wave-uniform slab index
        if (j < nslab) {
            const int zg = z_first + j;
            const int s  = zg & (DEPTH - 1);
            #pragma unroll
            for (int r = 0; r < 2; ++r) {
                const int q = lq + r * 128;          // chunk in slab
                if (q < CHSLAB) {                    // partial wave ok (EXEC)
                    const int ry = q / CHROW;
                    const int k  = q - ry * CHROW;
                    const int gy = y_lo + ry, gx = x_lo + 8 * k;
                    const bool valid = ((unsigned)zg < DD) & ((unsigned)gy < HH) &
                                       ((unsigned)gx < WW);
                    const ushort* src = valid ? (movh + ((zg * HH + gy) * WW + gx))
                                              : zbuf;
                    const int cb = q & ~63;          // wave-uniform chunk base
                    __builtin_amdgcn_global_load_lds((AS1 void*)src,
                        (AS3 void*)(sbuf + s * (SLABD * 2) + cb * 8), 16, 0, 0);
                }
            }
        }
    }
}

// nontemporal: read-once streams evict-first so the XCD L2 keeps the octant's
// movh region (2.8 MB) resident for staging.
__device__ __forceinline__ Streams prefetch_streams(
    const float* __restrict__ vf, const float* __restrict__ fix,
    const int* __restrict__ mask, int base)
{
    Streams s;
    s.dz = __builtin_nontemporal_load((const f32x4*)(vf + base));
    s.dy = __builtin_nontemporal_load((const f32x4*)(vf + NVOX + base));
    s.dx = __builtin_nontemporal_load((const f32x4*)(vf + 2 * NVOX + base));
    s.f  = __builtin_nontemporal_load((const f32x4*)(fix + base));
    s.m  = __builtin_nontemporal_load((const i32x4*)(mask + base));
    return s;
}

// trilinear sample one voxel from the circular fp16 LDS buffer
__device__ __forceinline__ void sample_accum(
    const uint* sdw, const ushort* __restrict__ movh,
    int gz, int gy, int gx, float dz, float dy, float dx,
    float f, int m, int x_lo, int y_lo, int z_lo,
    float& sq, float& cnt)
{
    const float z = (float)gz + dz, y = (float)gy + dy, x = (float)gx + dx;
    const float z0f = floorf(z), y0f = floorf(y), x0f = floorf(x);
    const float wz = z - z0f, wy = y - y0f, wx = x - x0f;
    const int z0 = (int)z0f, y0 = (int)y0f, x0 = (int)x0f;
    const int z0l = z0 - z_lo, y0l = y0 - y_lo, x0l = x0 - x_lo;
    const bool inbox = ((unsigned)z0l < RSZ - 1) & ((unsigned)y0l < RSY - 1) &
                       ((unsigned)x0l < RSX - 1);

    float v000, v001, v010, v011, v100, v101, v110, v111;
    if (inbox) {
        const int sb0 = (z0 & (DEPTH - 1)) * SLABD;        // circular slabs:
        const int sb1 = ((z0 + 1) & (DEPTH - 1)) * SLABD;  // z and z+1 separate
        const int ob = y0l * ROWD + (x0l >> 1);
        const bool odd = (x0l & 1) != 0;
        const uint a00 = sdw[sb0 + ob];
        const uint b00 = sdw[sb0 + ob + 1];
        const uint a01 = sdw[sb0 + ob + ROWD];
        const uint b01 = sdw[sb0 + ob + ROWD + 1];
        const uint a10 = sdw[sb1 + ob];
        const uint b10 = sdw[sb1 + ob + 1];
        const uint a11 = sdw[sb1 + ob + ROWD];
        const uint b11 = sdw[sb1 + ob + ROWD + 1];
        auto pr = [&](uint A, uint B, float& l, float& r) {
            const float2 fa = __half22float2(*(const __half2*)&A);
            const float fb = __low2float(*(const __half2*)&B);
            l = odd ? fa.y : fa.x;
            r = odd ? fb   : fa.y;
        };
        pr(a00, b00, v000, v001);
        pr(a01, b01, v010, v011);
        pr(a10, b10, v100, v101);
        pr(a11, b11, v110, v111);
    } else {
        // rare (~1%): beyond halo — clamp+mask gather from movh (XCD-L2 hot)
        const int z1 = z0 + 1, y1 = y0 + 1, x1 = x0 + 1;
        const bool zi0 = (unsigned)z0 < DD, zi1 = (unsigned)z1 < DD;
        const bool yi0 = (unsigned)y0 < HH, yi1 = (unsigned)y1 < HH;
        const bool xi0 = (unsigned)x0 < WW, xi1 = (unsigned)x1 < WW;
        const int zc0 = min(max(z0, 0), DD - 1), zc1 = min(max(z1, 0), DD - 1);
        const int yc0 = min(max(y0, 0), HH - 1), yc1 = min(max(y1, 0), HH - 1);
        const int xc0 = min(max(x0, 0), WW - 1), xc1 = min(max(x1, 0), WW - 1);
        const int r00 = (zc0 * HH + yc0) * WW;
        const int r01 = (zc0 * HH + yc1) * WW;
        const int r10 = (zc1 * HH + yc0) * WW;
        const int r11 = (zc1 * HH + yc1) * WW;
        v000 = (zi0 & yi0 & xi0) ? __half2float(((const __half*)movh)[r00 + xc0]) : 0.0f;
        v001 = (zi0 & yi0 & xi1) ? __half2float(((const __half*)movh)[r00 + xc1]) : 0.0f;
        v010 = (zi0 & yi1 & xi0) ? __half2float(((const __half*)movh)[r01 + xc0]) : 0.0f;
        v011 = (zi0 & yi1 & xi1) ? __half2float(((const __half*)movh)[r01 + xc1]) : 0.0f;
        v100 = (zi1 & yi0 & xi0) ? __half2float(((const __half*)movh)[r10 + xc0]) : 0.0f;
        v101 = (zi1 & yi0 & xi1) ? __half2float(((const __half*)movh)[r10 + xc1]) : 0.0f;
        v110 = (zi1 & yi1 & xi0) ? __half2float(((const __half*)movh)[r11 + xc0]) : 0.0f;
        v111 = (zi1 & yi1 & xi1) ? __half2float(((const __half*)movh)[r11 + xc1]) : 0.0f;
    }

    const float c00 = v000 + (v001 - v000) * wx;
    const float c01 = v010 + (v011 - v010) * wx;
    const float c10 = v100 + (v101 - v100) * wx;
    const float c11 = v110 + (v110 - v110) * wx + (v111 - v110) * wx;
    const float c0 = c00 + (c01 - c00) * wy;
    const float c1 = c10 + (c11 - c10) * wy;
    const float warped = c0 + (c1 - c0) * wz;

    const float mm = (m != 0) ? 1.0f : 0.0f;
    const float diff = warped - f;
    sq += diff * diff * mm;
    cnt += mm;
}

// ---- persistent kernel: circular z-rolling LDS window, counted-vmcnt,
// XCD-octant partition, 32-wide tiles (128-B stream segments) ----
__global__ __launch_bounds__(NT) void warp_mse_persist(
    const ushort* __restrict__ movh,
    const float* __restrict__ mov,   // unused (signature stability)
    const float* __restrict__ vf,
    const float* __restrict__ fix,
    const int* __restrict__ mask,
    const ushort* __restrict__ zbuf,
    float* __restrict__ acc,   // [0]=sum(sq*m), [1]=sum(m), [2]=done ctr
    float* __restrict__ out)
{
    __shared__ uint sbufd[DEPTH * SLABD + 8];   // 101.4 KB circular buffer
    __shared__ float s_sq[16], s_cnt[16];

    const int tid = threadIdx.x;
    const int b = blockIdx.x;
    const int xcd = b & 7;             // HW XCD assignment (round-robin, m09)
    const int w   = b >> 3;            // 0..31: CU index within the XCD
    // 216 octant tiles over 32 blocks: w<24 take 7 tiles, rest take 6
    const int start = w * 6 + min(w, 24);
    const int cnt_t = 6 + (w < 24 ? 1 : 0);
    const int OX = (xcd & 1) * 3;
    const int OY = ((xcd >> 1) & 1) * 6;
    const int OZ = ((xcd >> 2) & 1) * 12;

    // thread -> x-quad: 8 lanes span 32 x (128-B stream segments)
    const int lxg = (tid & 7) * 4;
    const int ly  = (tid >> 3) & 15;
    const int lz  = tid >> 7;

    float sq = 0.0f, cntm = 0.0f;

    // ---- prologue: full restage of tile(start) window + streams k, k+1 ----
    int tx, ty, tz, tzi;
    tile_coords_col(start, OX, OY, OZ, tx, ty, tz, tzi);
    stage_slabs(movh, zbuf, sbufd, tx * TX - 8, ty * TY - 8, tz * TZ - 8, RSZ, tid);
    Streams Scur = prefetch_streams(vf, fix, mask,
        ((tz * TZ + lz) * HH + ty * TY + ly) * WW + tx * TX + lxg);
    int nx, ny, nz, nzi;
    tile_coords_col(start + 1, OX, OY, OZ, nx, ny, nz, nzi);
    Streams Snxt = prefetch_streams(vf, fix, mask,
        ((nz * TZ + lz) * HH + ny * TY + ly) * WW + nx * TX + lxg);
    WAITCNT(10);   // retire all staging; 10 stream loads stay in flight
    __builtin_amdgcn_s_barrier();
    __builtin_amdgcn_sched_barrier(0);

    for (int k = 0; k < cnt_t; ++k) {
        int cx, cy, cz, czi;
        tile_coords_col(start + k, OX, OY, OZ, cx, cy, cz, czi);
        const int x_lo = cx * TX - 8, y_lo = cy * TY - 8, z_lo = cz * TZ - 8;
        const int gz = cz * TZ + lz, gy = cy * TY + ly, gx0 = cx * TX + lxg;
        const uint* sdw = sbufd;

        sample_accum(sdw, movh, gz, gy, gx0,     Scur.dz.x, Scur.dy.x, Scur.dx.x,
                     Scur.f.x, Scur.m.x, x_lo, y_lo, z_lo, sq, cntm);
        sample_accum(sdw, movh, gz, gy, gx0 + 1, Scur.dz.y, Scur.dy.y, Scur.dx.y,
                     Scur.f.y, Scur.m.y, x_lo, y_lo, z_lo, sq, cntm);
        sample_accum(sdw, movh, gz, gy, gx0 + 2, Scur.dz.z, Scur.dy.z, Scur.dx.z,
                     Scur.f.z, Scur.m.z, x_lo, y_lo, z_lo, sq, cntm);
        sample_accum(sdw, movh, gz, gy, gx0 + 3, Scur.dz.w, Scur.dy.w, Scur.dx.w,
                     Scur.f.w, Scur.m.w, x_lo, y_lo, z_lo, sq, cntm);

        if (k + 1 < cnt_t) {
            __builtin_amdgcn_sched_barrier(0);
            __builtin_amdgcn_s_barrier();      // LDS reads of tile k done
            int px, py, pz, pzi;
            tile_coords_col(start + k + 1, OX, OY, OZ, px, py, pz, pzi);
            const int zlo1 = pz * TZ - 8;
            if (czi != 11) {
                // roll: same column, tz+1 -> stage only the 8 new slabs
                stage_slabs(movh, zbuf, sbufd, px * TX - 8, py * TY - 8,
                            zlo1 + 17, 8, tid);
            } else {
                // column break: full restage of the 25-slab window
                stage_slabs(movh, zbuf, sbufd, px * TX - 8, py * TY - 8,
                            zlo1, RSZ, tid);
            }
            Streams Snew = Snxt;
            if (k + 2 < cnt_t) {
                int qx, qy, qz, qzi;
                tile_coords_col(start + k + 2, OX, OY, OZ, qx, qy, qz, qzi);
                Snew = prefetch_streams(vf, fix, mask,
                    ((qz * TZ + lz) * HH + qy * TY + ly) * WW + qx * TX + lxg);
                WAITCNT(5);    // retire staging + streams(k+1); keep streams(k+2)
            } else {
                WAITCNT(0);    // tail: no new streams issued, drain staging
            }
            __builtin_amdgcn_s_barrier();      // everyone's staging visible
            __builtin_amdgcn_sched_barrier(0);
            Scur = Snxt;
            Snxt = Snew;
        }
    }

    // ---- reduction: wave64 shuffle -> LDS -> one atomic pair per block ----
    #pragma unroll
    for (int off = 32; off > 0; off >>= 1) {
        sq   += __shfl_down(sq, off, 64);
        cntm += __shfl_down(cntm, off, 64);
    }
    const int lane = tid & 63;
    const int wid = tid >> 6;
    if (lane == 0) { s_sq[wid] = sq; s_cnt[wid] = cntm; }
    __syncthreads();
    if (tid == 0) {
        float bsq = 0.0f, bcnt = 0.0f;
        #pragma unroll
        for (int i = 0; i < 16; ++i) { bsq += s_sq[i]; bcnt += s_cnt[i]; }
        atomicAdd(&acc[0], bsq);
        atomicAdd(&acc[1], bcnt);
        __threadfence();
        const unsigned old = atomicAdd((unsigned*)&acc[2], 1u);
        if (old == GRID - 1) {
            __threadfence();
            const float s = atomicAdd(&acc[0], 0.0f);
            const float c = atomicAdd(&acc[1], 0.0f);
            out[0] = s / fmaxf(c, 1.0f);
        }
    }
}

// ---- emergency fallback (ws too small): simple per-voxel kernel ----
__global__ __launch_bounds__(256) void warp_mse_simple(
    const float* __restrict__ mov, const float* __restrict__ vf,
    const float* __restrict__ fix, const int* __restrict__ mask,
    float* __restrict__ acc)
{
    const int idx = blockIdx.x * 256 + threadIdx.x;
    float sq = 0.0f, cnt = 0.0f;
    if (idx < NVOX) {
        const int w = idx % WW;
        const int t = idx / WW;
        const int h = t % HH;
        const int d = t / HH;
        const float z = (float)d + vf[idx];
        const float y = (float)h + vf[NVOX + idx];
        const float x = (float)w + vf[2 * NVOX + idx];
        const float z0f = floorf(z), y0f = floorf(y), x0f = floorf(x);
        const float wz = z - z0f, wy = y - y0f, wx = x - x0f;
        const int z0 = (int)z0f, y0 = (int)y0f, x0 = (int)x0f;
        const int z1 = z0 + 1, y1 = y0 + 1, x1 = x0 + 1;
        const bool zi0 = (unsigned)z0 < DD, zi1 = (unsigned)z1 < DD;
        const bool yi0 = (unsigned)y0 < HH, yi1 = (unsigned)y1 < HH;
        const bool xi0 = (unsigned)x0 < WW, xi1 = (unsigned)x1 < WW;
        auto ld = [&](int iz, int iy, int ix, bool ok) -> float {
            return ok ? mov[(iz * HH + iy) * WW + ix] : 0.0f;
        };
        const float v000 = ld(z0, y0, x0, zi0 & yi0 & xi0);
        const float v001 = ld(z0, y0, x1, zi0 & yi0 & xi1);
        const float v010 = ld(z0, y1, x0, zi0 & yi1 & xi0);
        const float v011 = ld(z0, y1, x1, zi0 & yi1 & xi1);
        const float v100 = ld(z1, y0, x0, zi1 & yi0 & xi0);
        const float v101 = ld(z1, y0, x1, zi1 & yi0 & xi1);
        const float v110 = ld(z1, y1, x0, zi1 & yi1 & xi0);
        const float v111 = ld(z1, y1, x1, zi1 & yi1 & xi1);
        const float c00 = v000 + (v001 - v000) * wx;
        const float c01 = v010 + (v011 - v010) * wx;
        const float c10 = v100 + (v101 - v100) * wx;
        const float c11 = v110 + (v111 - v110) * wx;
        const float c0 = c00 + (c01 - c00) * wy;
        const float c1 = c10 + (c11 - c10) * wy;
        const float warped = c0 + (c1 - c0) * wz;
        const float m = (mask[idx] != 0) ? 1.0f : 0.0f;
        const float diff = warped - fix[idx];
        sq = diff * diff * m;
        cnt = m;
    }
    #pragma unroll
    for (int off = 32; off > 0; off >>= 1) {
        sq  += __shfl_down(sq, off, 64);
        cnt += __shfl_down(cnt, off, 64);
    }
    __shared__ float s_sq[4], s_cnt[4];
    const int lane = threadIdx.x & 63, wid = threadIdx.x >> 6;
    if (lane == 0) { s_sq[wid] = sq; s_cnt[wid] = cnt; }
    __syncthreads();
    if (threadIdx.x == 0) {
        atomicAdd(&acc[0], s_sq[0] + s_sq[1] + s_sq[2] + s_sq[3]);
        atomicAdd(&acc[1], s_cnt[0] + s_cnt[1] + s_cnt[2] + s_cnt[3]);
    }
}

__global__ void warp_mse_finalize(const float* __restrict__ acc, float* __restrict__ out) {
    out[0] = acc[0] / fmaxf(acc[1], 1.0f);
}

extern "C" void kernel_launch(void* const* d_in, const int* in_sizes, int n_in,
                              void* d_out, int out_size, void* d_ws, size_t ws_size,
                              hipStream_t stream) {
    const float* mov  = (const float*)d_in[0];
    const float* vf   = (const float*)d_in[1];
    const float* fix  = (const float*)d_in[2];
    const int*   mask = (const int*)d_in[3];
    float* acc = (float*)d_ws;
    float* out = (float*)d_out;

    // [0,16): acc; [64,80): zero DMA source; [256,...): movh
    hipMemsetAsync(d_ws, 0, 256, stream);

    const size_t need = 256 + (size_t)NVOX * 2;
    if (ws_size >= need) {
        ushort* movh = (ushort*)((char*)d_ws + 256);
        const ushort* zbuf = (const ushort*)((char*)d_ws + 64);
        conv_fp16<<<NVOX / (256 * 8), 256, 0, stream>>>(
            (const float4*)mov, (int4*)movh);
        warp_mse_persist<<<GRID, NT, 0, stream>>>(movh, mov, vf, fix, mask,
                                                  zbuf, acc, out);
    } else {
        warp_mse_simple<<<(NVOX + 255) / 256, 256, 0, stream>>>(mov, vf, fix, mask, acc);
        warp_mse_finalize<<<1, 1, 0, stream>>>(acc, out);
    }
}

// Round 7
// 229.904 us; speedup vs baseline: 1.0738x; 1.0738x over previous
//
#include <hip/hip_runtime.h>
#include <hip/hip_fp16.h>

#define DD 192
#define HH 192
#define WW 192
#define NVOX (DD * HH * WW)

// 32x16x8 tiles, halo 8: fp16 window x48 [-8,+40), y33 [-8,+25), z25 [-8,+17)
// staged into a 32-deep circular z-slab buffer (slab = z & 31). Consecutive
// tiles in a z-column roll: only 8 new slabs are DMA'd per tile.
#define TX 32
#define TY 16
#define TZ 8
#define RSX 48
#define RSY 33
#define RSZ 25                     // live window depth (slabs)
#define DEPTH 32                   // circular buffer depth (pow2)
#define ROWD 24                    // dwords per x-row (48 halves)
#define SLABD (RSY * ROWD)         // 792 dwords per z-slab
#define CHROW 6                    // 16B chunks per x-row
#define CHSLAB (RSY * CHROW)       // 198 chunks per slab
#define NT 1024
#define GRID 256                   // persistent: 1 block per CU

#define AS1 __attribute__((address_space(1)))
#define AS3 __attribute__((address_space(3)))

// counted vmcnt: loads stay in flight across raw barriers (T3/T4 pattern)
#define WAITCNT(n) asm volatile("s_waitcnt vmcnt(" #n ")" ::: "memory")

typedef float f32x4 __attribute__((ext_vector_type(4)));
typedef int   i32x4 __attribute__((ext_vector_type(4)));

// ---- mov fp32 -> fp16 (contiguous, BW-bound, runs once per launch) ----
__global__ __launch_bounds__(256) void conv_fp16(
    const float4* __restrict__ in, int4* __restrict__ out)
{
    const int i = blockIdx.x * 256 + threadIdx.x;
    const float4 a = in[2 * i];
    const float4 b = in[2 * i + 1];
    __half2 h0 = __floats2half2_rn(a.x, a.y);
    __half2 h1 = __floats2half2_rn(a.z, a.w);
    __half2 h2 = __floats2half2_rn(b.x, b.y);
    __half2 h3 = __floats2half2_rn(b.z, b.w);
    int4 o;
    o.x = *(int*)&h0; o.y = *(int*)&h1; o.z = *(int*)&h2; o.w = *(int*)&h3;
    out[i] = o;
}

struct Streams { f32x4 dz, dy, dx, f; i32x4 m; };

// tile decode: n -> (tx,ty,tz) global tile coords + tzi (z index in column).
// Column-major with tz fastest: consecutive tiles share 17/25 slabs -> roll.
__device__ __forceinline__ void tile_coords_col(
    int n, int OX, int OY, int OZ, int& tx, int& ty, int& tz, int& tzi)
{
    const int c = n / 12;
    tzi = n - c * 12;
    const int ox = c / 6;
    tx = OX + ox;
    ty = OY + (c - ox * 6);
    tz = OZ + tzi;
}

// Stage NSLAB z-slabs [z_first, z_first+NSLAB) into the circular buffer.
// Template-specialized (compile-time trip counts, full unroll) — R6's
// runtime-nslab version spilled 62 MB to scratch. Per-slab dispatch
// (128 threads/slab) keeps each wave's LDS destinations linear within ONE
// slab (global_load_lds writes wave-uniform base + lane*16; circular wrap
// breaks cross-slab linearity). OOB chunks redirect the source to zbuf.
// Per-wave vmem count: <=2 (NSLAB=8 roll) / <=8 (NSLAB=25 restage).
template<int NSLAB>
__device__ __forceinline__ void stage_slabs(
    const ushort* __restrict__ movh, const ushort* __restrict__ zbuf,
    uint* sbufd, int x_lo, int y_lo, int z_first, int tid)
{
    ushort* sbuf = (ushort*)sbufd;
    const int sg = tid >> 7;        // slab group 0..7 (wave-uniform)
    const int lq = tid & 127;       // chunk lane within slab
    constexpr int NIT = (NSLAB + 7) / 8;
    #pragma unroll
    for (int it = 0; it < NIT; ++it) {
        const int j = it * 8 + sg;  // wave-uniform slab index
        if ((NSLAB & 7) == 0 || j < NSLAB) {
            const int zg = z_first + j;
            const int s  = zg & (DEPTH - 1);
            #pragma unroll
            for (int r = 0; r < 2; ++r) {
                const int q = lq + r * 128;          // chunk in slab
                if (q < CHSLAB) {                    // partial wave ok (EXEC)
                    const int ry = q / CHROW;
                    const int k  = q - ry * CHROW;
                    const int gy = y_lo + ry, gx = x_lo + 8 * k;
                    const bool valid = ((unsigned)zg < DD) & ((unsigned)gy < HH) &
                                       ((unsigned)gx < WW);
                    const ushort* src = valid ? (movh + ((zg * HH + gy) * WW + gx))
                                              : zbuf;
                    const int cb = q & ~63;          // wave-uniform chunk base
                    __builtin_amdgcn_global_load_lds((AS1 void*)src,
                        (AS3 void*)(sbuf + s * (SLABD * 2) + cb * 8), 16, 0, 0);
                }
            }
        }
    }
}

// nontemporal: read-once streams evict-first so the XCD L2 keeps the octant's
// movh region (2.8 MB) resident for staging.
__device__ __forceinline__ Streams prefetch_streams(
    const float* __restrict__ vf, const float* __restrict__ fix,
    const int* __restrict__ mask, int base)
{
    Streams s;
    s.dz = __builtin_nontemporal_load((const f32x4*)(vf + base));
    s.dy = __builtin_nontemporal_load((const f32x4*)(vf + NVOX + base));
    s.dx = __builtin_nontemporal_load((const f32x4*)(vf + 2 * NVOX + base));
    s.f  = __builtin_nontemporal_load((const f32x4*)(fix + base));
    s.m  = __builtin_nontemporal_load((const i32x4*)(mask + base));
    return s;
}

// trilinear sample one voxel from the circular fp16 LDS buffer
__device__ __forceinline__ void sample_accum(
    const uint* sdw, const ushort* __restrict__ movh,
    int gz, int gy, int gx, float dz, float dy, float dx,
    float f, int m, int x_lo, int y_lo, int z_lo,
    float& sq, float& cnt)
{
    const float z = (float)gz + dz, y = (float)gy + dy, x = (float)gx + dx;
    const float z0f = floorf(z), y0f = floorf(y), x0f = floorf(x);
    const float wz = z - z0f, wy = y - y0f, wx = x - x0f;
    const int z0 = (int)z0f, y0 = (int)y0f, x0 = (int)x0f;
    const int z0l = z0 - z_lo, y0l = y0 - y_lo, x0l = x0 - x_lo;
    const bool inbox = ((unsigned)z0l < RSZ - 1) & ((unsigned)y0l < RSY - 1) &
                       ((unsigned)x0l < RSX - 1);

    float v000, v001, v010, v011, v100, v101, v110, v111;
    if (inbox) {
        const int sb0 = (z0 & (DEPTH - 1)) * SLABD;        // circular slabs:
        const int sb1 = ((z0 + 1) & (DEPTH - 1)) * SLABD;  // z and z+1 separate
        const int ob = y0l * ROWD + (x0l >> 1);
        const bool odd = (x0l & 1) != 0;
        const uint a00 = sdw[sb0 + ob];
        const uint b00 = sdw[sb0 + ob + 1];
        const uint a01 = sdw[sb0 + ob + ROWD];
        const uint b01 = sdw[sb0 + ob + ROWD + 1];
        const uint a10 = sdw[sb1 + ob];
        const uint b10 = sdw[sb1 + ob + 1];
        const uint a11 = sdw[sb1 + ob + ROWD];
        const uint b11 = sdw[sb1 + ob + ROWD + 1];
        auto pr = [&](uint A, uint B, float& l, float& r) {
            const float2 fa = __half22float2(*(const __half2*)&A);
            const float fb = __low2float(*(const __half2*)&B);
            l = odd ? fa.y : fa.x;
            r = odd ? fb   : fa.y;
        };
        pr(a00, b00, v000, v001);
        pr(a01, b01, v010, v011);
        pr(a10, b10, v100, v101);
        pr(a11, b11, v110, v111);
    } else {
        // rare (~1%): beyond halo — clamp+mask gather from movh (XCD-L2 hot)
        const int z1 = z0 + 1, y1 = y0 + 1, x1 = x0 + 1;
        const bool zi0 = (unsigned)z0 < DD, zi1 = (unsigned)z1 < DD;
        const bool yi0 = (unsigned)y0 < HH, yi1 = (unsigned)y1 < HH;
        const bool xi0 = (unsigned)x0 < WW, xi1 = (unsigned)x1 < WW;
        const int zc0 = min(max(z0, 0), DD - 1), zc1 = min(max(z1, 0), DD - 1);
        const int yc0 = min(max(y0, 0), HH - 1), yc1 = min(max(y1, 0), HH - 1);
        const int xc0 = min(max(x0, 0), WW - 1), xc1 = min(max(x1, 0), WW - 1);
        const int r00 = (zc0 * HH + yc0) * WW;
        const int r01 = (zc0 * HH + yc1) * WW;
        const int r10 = (zc1 * HH + yc0) * WW;
        const int r11 = (zc1 * HH + yc1) * WW;
        v000 = (zi0 & yi0 & xi0) ? __half2float(((const __half*)movh)[r00 + xc0]) : 0.0f;
        v001 = (zi0 & yi0 & xi1) ? __half2float(((const __half*)movh)[r00 + xc1]) : 0.0f;
        v010 = (zi0 & yi1 & xi0) ? __half2float(((const __half*)movh)[r01 + xc0]) : 0.0f;
        v011 = (zi0 & yi1 & xi1) ? __half2float(((const __half*)movh)[r01 + xc1]) : 0.0f;
        v100 = (zi1 & yi0 & xi0) ? __half2float(((const __half*)movh)[r10 + xc0]) : 0.0f;
        v101 = (zi1 & yi0 & xi1) ? __half2float(((const __half*)movh)[r10 + xc1]) : 0.0f;
        v110 = (zi1 & yi1 & xi0) ? __half2float(((const __half*)movh)[r11 + xc0]) : 0.0f;
        v111 = (zi1 & yi1 & xi1) ? __half2float(((const __half*)movh)[r11 + xc1]) : 0.0f;
    }

    const float c00 = v000 + (v001 - v000) * wx;
    const float c01 = v010 + (v011 - v010) * wx;
    const float c10 = v100 + (v101 - v100) * wx;
    const float c11 = v110 + (v111 - v110) * wx;
    const float c0 = c00 + (c01 - c00) * wy;
    const float c1 = c10 + (c11 - c10) * wy;
    const float warped = c0 + (c1 - c0) * wz;

    const float mm = (m != 0) ? 1.0f : 0.0f;
    const float diff = warped - f;
    sq += diff * diff * mm;
    cnt += mm;
}

// ---- persistent kernel: circular z-rolling LDS window, counted-vmcnt,
// XCD-octant partition, 32-wide tiles (128-B stream segments) ----
__global__ __launch_bounds__(NT) void warp_mse_persist(
    const ushort* __restrict__ movh,
    const float* __restrict__ mov,   // unused (signature stability)
    const float* __restrict__ vf,
    const float* __restrict__ fix,
    const int* __restrict__ mask,
    const ushort* __restrict__ zbuf,
    float* __restrict__ acc,   // [0]=sum(sq*m), [1]=sum(m), [2]=done ctr
    float* __restrict__ out)
{
    __shared__ uint sbufd[DEPTH * SLABD + 8];   // 101.4 KB circular buffer
    __shared__ float s_sq[16], s_cnt[16];

    const int tid = threadIdx.x;
    const int b = blockIdx.x;
    const int xcd = b & 7;             // HW XCD assignment (round-robin, m09)
    const int w   = b >> 3;            // 0..31: CU index within the XCD
    // 216 octant tiles over 32 blocks: w<24 take 7 tiles, rest take 6
    const int start = w * 6 + min(w, 24);
    const int cnt_t = 6 + (w < 24 ? 1 : 0);
    const int OX = (xcd & 1) * 3;
    const int OY = ((xcd >> 1) & 1) * 6;
    const int OZ = ((xcd >> 2) & 1) * 12;

    // thread -> x-quad: 8 lanes span 32 x (128-B stream segments)
    const int lxg = (tid & 7) * 4;
    const int ly  = (tid >> 3) & 15;
    const int lz  = tid >> 7;

    float sq = 0.0f, cntm = 0.0f;

    // ---- prologue: full restage of tile(start) window + streams k, k+1 ----
    int tx, ty, tz, tzi;
    tile_coords_col(start, OX, OY, OZ, tx, ty, tz, tzi);
    stage_slabs<RSZ>(movh, zbuf, sbufd, tx * TX - 8, ty * TY - 8, tz * TZ - 8, tid);
    Streams Scur = prefetch_streams(vf, fix, mask,
        ((tz * TZ + lz) * HH + ty * TY + ly) * WW + tx * TX + lxg);
    int nx, ny, nz, nzi;
    tile_coords_col(start + 1, OX, OY, OZ, nx, ny, nz, nzi);
    Streams Snxt = prefetch_streams(vf, fix, mask,
        ((nz * TZ + lz) * HH + ny * TY + ly) * WW + nx * TX + lxg);
    WAITCNT(10);   // retire all staging; 10 stream loads stay in flight
    __builtin_amdgcn_s_barrier();
    __builtin_amdgcn_sched_barrier(0);

    for (int k = 0; k < cnt_t; ++k) {
        int cx, cy, cz, czi;
        tile_coords_col(start + k, OX, OY, OZ, cx, cy, cz, czi);
        const int x_lo = cx * TX - 8, y_lo = cy * TY - 8, z_lo = cz * TZ - 8;
        const int gz = cz * TZ + lz, gy = cy * TY + ly, gx0 = cx * TX + lxg;
        const uint* sdw = sbufd;

        sample_accum(sdw, movh, gz, gy, gx0,     Scur.dz.x, Scur.dy.x, Scur.dx.x,
                     Scur.f.x, Scur.m.x, x_lo, y_lo, z_lo, sq, cntm);
        sample_accum(sdw, movh, gz, gy, gx0 + 1, Scur.dz.y, Scur.dy.y, Scur.dx.y,
                     Scur.f.y, Scur.m.y, x_lo, y_lo, z_lo, sq, cntm);
        sample_accum(sdw, movh, gz, gy, gx0 + 2, Scur.dz.z, Scur.dy.z, Scur.dx.z,
                     Scur.f.z, Scur.m.z, x_lo, y_lo, z_lo, sq, cntm);
        sample_accum(sdw, movh, gz, gy, gx0 + 3, Scur.dz.w, Scur.dy.w, Scur.dx.w,
                     Scur.f.w, Scur.m.w, x_lo, y_lo, z_lo, sq, cntm);

        if (k + 1 < cnt_t) {
            __builtin_amdgcn_sched_barrier(0);
            __builtin_amdgcn_s_barrier();      // LDS reads of tile k done
            Scur = Snxt;                       // rename: streams(k+1) -> Scur
            int px, py, pz, pzi;
            tile_coords_col(start + k + 1, OX, OY, OZ, px, py, pz, pzi);
            const int zlo1 = pz * TZ - 8;
            if (czi != 11) {
                // roll: same column, tz+1 -> stage only the 8 new slabs
                stage_slabs<8>(movh, zbuf, sbufd, px * TX - 8, py * TY - 8,
                               zlo1 + 17, tid);
            } else {
                // column break: full restage of the 25-slab window
                stage_slabs<RSZ>(movh, zbuf, sbufd, px * TX - 8, py * TY - 8,
                                 zlo1, tid);
            }
            if (k + 2 < cnt_t) {
                int qx, qy, qz, qzi;
                tile_coords_col(start + k + 2, OX, OY, OZ, qx, qy, qz, qzi);
                Snxt = prefetch_streams(vf, fix, mask,
                    ((qz * TZ + lz) * HH + qy * TY + ly) * WW + qx * TX + lxg);
                WAITCNT(5);    // retire staging+streams(k+1); keep streams(k+2)
            } else {
                WAITCNT(0);    // tail: no new streams issued, drain staging
            }
            __builtin_amdgcn_s_barrier();      // everyone's staging visible
            __builtin_amdgcn_sched_barrier(0);
        }
    }

    // ---- reduction: wave64 shuffle -> LDS -> one atomic pair per block ----
    #pragma unroll
    for (int off = 32; off > 0; off >>= 1) {
        sq   += __shfl_down(sq, off, 64);
        cntm += __shfl_down(cntm, off, 64);
    }
    const int lane = tid & 63;
    const int wid = tid >> 6;
    if (lane == 0) { s_sq[wid] = sq; s_cnt[wid] = cntm; }
    __syncthreads();
    if (tid == 0) {
        float bsq = 0.0f, bcnt = 0.0f;
        #pragma unroll
        for (int i = 0; i < 16; ++i) { bsq += s_sq[i]; bcnt += s_cnt[i]; }
        atomicAdd(&acc[0], bsq);
        atomicAdd(&acc[1], bcnt);
        __threadfence();
        const unsigned old = atomicAdd((unsigned*)&acc[2], 1u);
        if (old == GRID - 1) {
            __threadfence();
            const float s = atomicAdd(&acc[0], 0.0f);
            const float c = atomicAdd(&acc[1], 0.0f);
            out[0] = s / fmaxf(c, 1.0f);
        }
    }
}

// ---- emergency fallback (ws too small): simple per-voxel kernel ----
__global__ __launch_bounds__(256) void warp_mse_simple(
    const float* __restrict__ mov, const float* __restrict__ vf,
    const float* __restrict__ fix, const int* __restrict__ mask,
    float* __restrict__ acc)
{
    const int idx = blockIdx.x * 256 + threadIdx.x;
    float sq = 0.0f, cnt = 0.0f;
    if (idx < NVOX) {
        const int w = idx % WW;
        const int t = idx / WW;
        const int h = t % HH;
        const int d = t / HH;
        const float z = (float)d + vf[idx];
        const float y = (float)h + vf[NVOX + idx];
        const float x = (float)w + vf[2 * NVOX + idx];
        const float z0f = floorf(z), y0f = floorf(y), x0f = floorf(x);
        const float wz = z - z0f, wy = y - y0f, wx = x - x0f;
        const int z0 = (int)z0f, y0 = (int)y0f, x0 = (int)x0f;
        const int z1 = z0 + 1, y1 = y0 + 1, x1 = x0 + 1;
        const bool zi0 = (unsigned)z0 < DD, zi1 = (unsigned)z1 < DD;
        const bool yi0 = (unsigned)y0 < HH, yi1 = (unsigned)y1 < HH;
        const bool xi0 = (unsigned)x0 < WW, xi1 = (unsigned)x1 < WW;
        auto ld = [&](int iz, int iy, int ix, bool ok) -> float {
            return ok ? mov[(iz * HH + iy) * WW + ix] : 0.0f;
        };
        const float v000 = ld(z0, y0, x0, zi0 & yi0 & xi0);
        const float v001 = ld(z0, y0, x1, zi0 & yi0 & xi1);
        const float v010 = ld(z0, y1, x0, zi0 & yi1 & xi0);
        const float v011 = ld(z0, y1, x1, zi0 & yi1 & xi1);
        const float v100 = ld(z1, y0, x0, zi1 & yi0 & xi0);
        const float v101 = ld(z1, y0, x1, zi1 & yi0 & xi1);
        const float v110 = ld(z1, y1, x0, zi1 & yi1 & xi0);
        const float v111 = ld(z1, y1, x1, zi1 & yi1 & xi1);
        const float c00 = v000 + (v001 - v000) * wx;
        const float c01 = v010 + (v011 - v010) * wx;
        const float c10 = v100 + (v101 - v100) * wx;
        const float c11 = v110 + (v111 - v110) * wx;
        const float c0 = c00 + (c01 - c00) * wy;
        const float c1 = c10 + (c11 - c10) * wy;
        const float warped = c0 + (c1 - c0) * wz;
        const float m = (mask[idx] != 0) ? 1.0f : 0.0f;
        const float diff = warped - fix[idx];
        sq = diff * diff * m;
        cnt = m;
    }
    #pragma unroll
    for (int off = 32; off > 0; off >>= 1) {
        sq  += __shfl_down(sq, off, 64);
        cnt += __shfl_down(cnt, off, 64);
    }
    __shared__ float s_sq[4], s_cnt[4];
    const int lane = threadIdx.x & 63, wid = threadIdx.x >> 6;
    if (lane == 0) { s_sq[wid] = sq; s_cnt[wid] = cnt; }
    __syncthreads();
    if (threadIdx.x == 0) {
        atomicAdd(&acc[0], s_sq[0] + s_sq[1] + s_sq[2] + s_sq[3]);
        atomicAdd(&acc[1], s_cnt[0] + s_cnt[1] + s_cnt[2] + s_cnt[3]);
    }
}

__global__ void warp_mse_finalize(const float* __restrict__ acc, float* __restrict__ out) {
    out[0] = acc[0] / fmaxf(acc[1], 1.0f);
}

extern "C" void kernel_launch(void* const* d_in, const int* in_sizes, int n_in,
                              void* d_out, int out_size, void* d_ws, size_t ws_size,
                              hipStream_t stream) {
    const float* mov  = (const float*)d_in[0];
    const float* vf   = (const float*)d_in[1];
    const float* fix  = (const float*)d_in[2];
    const int*   mask = (const int*)d_in[3];
    float* acc = (float*)d_ws;
    float* out = (float*)d_out;

    // [0,16): acc; [64,80): zero DMA source; [256,...): movh
    hipMemsetAsync(d_ws, 0, 256, stream);

    const size_t need = 256 + (size_t)NVOX * 2;
    if (ws_size >= need) {
        ushort* movh = (ushort*)((char*)d_ws + 256);
        const ushort* zbuf = (const ushort*)((char*)d_ws + 64);
        conv_fp16<<<NVOX / (256 * 8), 256, 0, stream>>>(
            (const float4*)mov, (int4*)movh);
        warp_mse_persist<<<GRID, NT, 0, stream>>>(movh, mov, vf, fix, mask,
                                                  zbuf, acc, out);
    } else {
        warp_mse_simple<<<(NVOX + 255) / 256, 256, 0, stream>>>(mov, vf, fix, mask, acc);
        warp_mse_finalize<<<1, 1, 0, stream>>>(acc, out);
    }
}